// Round 1
// baseline (305.128 us; speedup 1.0000x reference)
//
#include <hip/hip_runtime.h>
#include <math.h>

// Problem constants (match reference setup_inputs)
namespace {
constexpr int NEL   = 4;
constexpr int NEXP  = 16;
constexpr int Bb    = 128;   // batches
constexpr int Aa    = 128;   // atoms per batch
constexpr int Cc    = 256;   // pairs per batch
constexpr int FATOM = 176;
constexpr int FPAIR = 32;
constexpr int FIN   = 384;   // 2*FATOM + FPAIR
constexpr int HH1   = 128;
constexpr int HH2   = 96;
constexpr int FOUT  = 2;
constexpr int NP    = Bb * Cc;      // 32768 pairs
constexpr int TILE_P = 32;          // pairs per MoE tile
constexpr int MAX_TILES = NP / TILE_P + NEXP;  // 1040 upper bound
}

// ws int layout:
//   [0, 32768)        nn_index per pair
//   [32768, 65536)    expert-sorted pair ids
//   [65536, +16)      counts
//   [65552, +17)      offsets (exclusive scan)
//   [65576, +16)      cur (scatter cursors)
//   [65600, +17)      tile_prefix

__global__ void k_index(const int* __restrict__ conn,
                        const int* __restrict__ elements,
                        int* __restrict__ nn,
                        int* __restrict__ counts,
                        float* __restrict__ out)
{
    __shared__ int sh[NEXP];
    int t = threadIdx.x;
    if (t < NEXP) sh[t] = 0;
    __syncthreads();
    int p = blockIdx.x * blockDim.x + t;
    int my_nn = -1;
    if (p < NP) {
        int c0 = conn[2 * p], c1 = conn[2 * p + 1];
        if (c0 != -1) {
            int b = p / Cc;
            int i0 = b * Aa + c0; if (i0 < 0) i0 += Bb * Aa;  // python negative-wrap safety
            int i1 = b * Aa + c1; if (i1 < 0) i1 += Bb * Aa;
            int e0 = elements[i0], e1 = elements[i1];
            my_nn = e0 * NEL + e1;
        }
        if (my_nn < 0 || my_nn >= NEXP) {
            out[2 * p] = 0.f;
            out[2 * p + 1] = 0.f;
            my_nn = -1;
        }
        nn[p] = my_nn;
        if (my_nn >= 0) atomicAdd(&sh[my_nn], 1);
    }
    __syncthreads();
    if (t < NEXP && sh[t] > 0) atomicAdd(&counts[t], sh[t]);
}

__global__ void k_scan(const int* __restrict__ counts,
                       int* __restrict__ offsets,
                       int* __restrict__ cur,
                       int* __restrict__ tprefix)
{
    if (threadIdx.x == 0) {
        int acc = 0, tacc = 0;
        for (int e = 0; e < NEXP; ++e) {
            offsets[e] = acc;
            cur[e] = acc;
            tprefix[e] = tacc;
            acc += counts[e];
            tacc += (counts[e] + TILE_P - 1) / TILE_P;
        }
        offsets[NEXP] = acc;
        tprefix[NEXP] = tacc;
    }
}

__global__ void k_scatter(const int* __restrict__ nn,
                          int* __restrict__ cur,
                          int* __restrict__ sorted)
{
    __shared__ int sh_cnt[NEXP], sh_base[NEXP];
    int t = threadIdx.x;
    if (t < NEXP) sh_cnt[t] = 0;
    __syncthreads();
    int p = blockIdx.x * blockDim.x + t;
    int e = -1, r = 0;
    if (p < NP) {
        e = nn[p];
        if (e >= 0) r = atomicAdd(&sh_cnt[e], 1);
    }
    __syncthreads();
    if (t < NEXP && sh_cnt[t] > 0) sh_base[t] = atomicAdd(&cur[t], sh_cnt[t]);
    __syncthreads();
    if (p < NP && e >= 0) sorted[sh_base[e] + r] = p;
}

__global__ __launch_bounds__(128) void k_moe(
    const int* __restrict__ sorted,
    const int* __restrict__ offsets,
    const int* __restrict__ tprefix,
    const int* __restrict__ conn,
    const float* __restrict__ sym,
    const float* __restrict__ pairf,
    const float* __restrict__ W1, const float* __restrict__ b1,
    const float* __restrict__ W2, const float* __restrict__ b2,
    const float* __restrict__ W3, const float* __restrict__ b3,
    float* __restrict__ out)
{
    __shared__ float Xs[TILE_P][FIN];    // 48 KB
    __shared__ float H1s[TILE_P][HH1];   // 16 KB
    __shared__ float H2s[TILE_P][HH2];   // 12 KB
    __shared__ int rows[TILE_P];

    int tile = blockIdx.x;
    int total = tprefix[NEXP];
    if (tile >= total) return;
    int e = 0;
    while (tile >= tprefix[e + 1]) e++;
    int t0 = tile - tprefix[e];
    int seg_begin = offsets[e] + t0 * TILE_P;
    int cnt = offsets[e + 1] - seg_begin;
    if (cnt > TILE_P) cnt = TILE_P;

    int t = threadIdx.x;
    if (t < TILE_P) rows[t] = (t < cnt) ? sorted[seg_begin + t] : -1;
    __syncthreads();

    // Gather X tile: [fa(176) | fb(176) | pf(32)] per row
    for (int r = 0; r < cnt; ++r) {
        int p = rows[r];
        int b = p / Cc;
        int c0 = conn[2 * p], c1 = conn[2 * p + 1];
        int i0 = b * Aa + c0; if (i0 < 0) i0 += Bb * Aa;
        int i1 = b * Aa + c1; if (i1 < 0) i1 += Bb * Aa;
        const float* fa = sym + (size_t)i0 * FATOM;
        const float* fb = sym + (size_t)i1 * FATOM;
        const float* pf = pairf + (size_t)p * FPAIR;
        for (int f = t; f < FIN; f += 128) {
            float v;
            if (f < FATOM)          v = fa[f];
            else if (f < 2 * FATOM) v = fb[f - FATOM];
            else                    v = pf[f - 2 * FATOM];
            Xs[r][f] = v;
        }
    }
    __syncthreads();

    // ---- Layer 1: [32 x 384] @ [384 x 128], thread t owns fout t ----
    const float* W1e = W1 + (size_t)e * FIN * HH1;
    float acc[TILE_P];
#pragma unroll
    for (int r = 0; r < TILE_P; ++r) acc[r] = 0.f;
    for (int k = 0; k < FIN; k += 4) {
        float w0 = W1e[(size_t)(k + 0) * HH1 + t];
        float w1 = W1e[(size_t)(k + 1) * HH1 + t];
        float w2 = W1e[(size_t)(k + 2) * HH1 + t];
        float w3 = W1e[(size_t)(k + 3) * HH1 + t];
#pragma unroll
        for (int r = 0; r < TILE_P; ++r) {
            float4 x = *(const float4*)&Xs[r][k];
            acc[r] = fmaf(x.w, w3, fmaf(x.z, w2, fmaf(x.y, w1, fmaf(x.x, w0, acc[r]))));
        }
    }
    {
        float bb = b1[e * HH1 + t];
#pragma unroll
        for (int r = 0; r < TILE_P; ++r) {
            float v = acc[r] + bb;
            H1s[r][t] = v > 0.f ? v : expm1f(v);   // celu alpha=1
        }
    }
    __syncthreads();

    // ---- Layer 2: [32 x 128] @ [128 x 96], threads 0..95 own fout ----
    if (t < HH2) {
        const float* W2e = W2 + (size_t)e * HH1 * HH2;
        float acc2[TILE_P];
#pragma unroll
        for (int r = 0; r < TILE_P; ++r) acc2[r] = 0.f;
        for (int k = 0; k < HH1; k += 4) {
            float w0 = W2e[(size_t)(k + 0) * HH2 + t];
            float w1 = W2e[(size_t)(k + 1) * HH2 + t];
            float w2 = W2e[(size_t)(k + 2) * HH2 + t];
            float w3 = W2e[(size_t)(k + 3) * HH2 + t];
#pragma unroll
            for (int r = 0; r < TILE_P; ++r) {
                float4 x = *(const float4*)&H1s[r][k];
                acc2[r] = fmaf(x.w, w3, fmaf(x.z, w2, fmaf(x.y, w1, fmaf(x.x, w0, acc2[r]))));
            }
        }
        float bb = b2[e * HH2 + t];
#pragma unroll
        for (int r = 0; r < TILE_P; ++r) {
            float v = acc2[r] + bb;
            H2s[r][t] = v > 0.f ? v : expm1f(v);
        }
    }
    __syncthreads();

    // ---- Layer 3: [32 x 96] @ [96 x 2], thread t -> (pair t/2, out t%2) ----
    if (t < TILE_P * FOUT) {
        int r = t / FOUT, o = t % FOUT;
        if (r < cnt) {
            const float* W3e = W3 + (size_t)e * HH2 * FOUT;
            float s = b3[e * FOUT + o];
#pragma unroll 8
            for (int k = 0; k < HH2; ++k)
                s = fmaf(H2s[r][k], W3e[k * FOUT + o], s);
            int p = rows[r];
            out[(size_t)p * FOUT + o] = s;
        }
    }
}

extern "C" void kernel_launch(void* const* d_in, const int* in_sizes, int n_in,
                              void* d_out, int out_size, void* d_ws, size_t ws_size,
                              hipStream_t stream)
{
    const int*   elements = (const int*)d_in[0];
    const int*   conn     = (const int*)d_in[1];
    const float* sym      = (const float*)d_in[2];
    const float* pairf    = (const float*)d_in[3];
    const float* W1       = (const float*)d_in[4];
    const float* b1       = (const float*)d_in[5];
    const float* W2       = (const float*)d_in[6];
    const float* b2       = (const float*)d_in[7];
    const float* W3       = (const float*)d_in[8];
    const float* b3       = (const float*)d_in[9];
    float* out = (float*)d_out;

    int* wsi     = (int*)d_ws;
    int* nn      = wsi;
    int* sorted  = wsi + 32768;
    int* counts  = wsi + 65536;
    int* offsets = wsi + 65552;
    int* cur     = wsi + 65576;
    int* tprefix = wsi + 65600;

    hipMemsetAsync((void*)counts, 0, NEXP * sizeof(int), stream);

    k_index<<<NP / 256, 256, 0, stream>>>(conn, elements, nn, counts, out);
    k_scan<<<1, 64, 0, stream>>>(counts, offsets, cur, tprefix);
    k_scatter<<<NP / 256, 256, 0, stream>>>(nn, cur, sorted);
    k_moe<<<MAX_TILES, 128, 0, stream>>>(sorted, offsets, tprefix, conn,
                                         sym, pairf, W1, b1, W2, b2, W3, b3, out);
}

// Round 2
// 64.926 us; speedup vs baseline: 4.6996x; 4.6996x over previous
//
#include <hip/hip_runtime.h>
#include <math.h>

typedef __attribute__((ext_vector_type(8))) short short8;
typedef __attribute__((ext_vector_type(4))) float f32x4;

namespace {
constexpr int NEL   = 4;
constexpr int NEXP  = 16;
constexpr int Bb    = 128;
constexpr int Aa    = 128;
constexpr int Cc    = 256;
constexpr int FATOM = 176;
constexpr int FPAIR = 32;
constexpr int FIN   = 384;
constexpr int HH1   = 128;
constexpr int HH2   = 96;
constexpr int NP    = Bb * Cc;               // 32768
constexpr int TILE_P = 32;
constexpr int MAX_TILES = NP / TILE_P + NEXP; // 1040

// ws element offsets
constexpr int WS_NN      = 0;
constexpr int WS_SORTED  = 32768;
constexpr int WS_COUNTS  = 65536;
constexpr int WS_OFFSETS = 65552;
constexpr int WS_CUR     = 65576;
constexpr int WS_TPREFIX = 65600;
constexpr int WS_BF_SHORT = 147456;          // byte 294912, 16B aligned
constexpr int SYM_N   = Bb * Aa * FATOM;     // 2,883,584
constexpr int PAIR_N  = Bb * Cc * FPAIR;     // 1,048,576
constexpr int W1T_N   = NEXP * HH1 * FIN;    // 786,432
constexpr int W2T_N   = NEXP * HH2 * HH1;    // 196,608
}

__device__ inline float bf2f(short s) {
    unsigned u = ((unsigned)(unsigned short)s) << 16;
    return __builtin_bit_cast(float, u);
}
__device__ inline short f2bf(float f) {
    unsigned u = __builtin_bit_cast(unsigned, f);
    unsigned r = (u + 0x7FFFu + ((u >> 16) & 1u)) >> 16;
    return (short)r;
}

// ---- convert sym_features + pair_features fp32 -> bf16 (vectorized) ----
__global__ void k_cvt_x(const float* __restrict__ sym, const float* __restrict__ pairf,
                        short* __restrict__ symb, short* __restrict__ pairfb)
{
    int i = blockIdx.x * 256 + threadIdx.x;          // one float4 per thread
    constexpr int NS4 = SYM_N / 4;                   // 720,896
    constexpr int NT4 = NS4 + PAIR_N / 4;            // 983,040
    if (i >= NT4) return;
    const float4* src; short* dst; int j;
    if (i < NS4) { src = (const float4*)sym;   dst = symb;   j = i; }
    else         { src = (const float4*)pairf; dst = pairfb; j = i - NS4; }
    float4 v = src[j];
    short4 o;
    o.x = f2bf(v.x); o.y = f2bf(v.y); o.z = f2bf(v.z); o.w = f2bf(v.w);
    *(short4*)(dst + 4 * (size_t)j) = o;
}

// ---- transpose+convert W1,W2 -> bf16 [e][n][k] ----
__global__ void k_cvt_w(const float* __restrict__ W1, const float* __restrict__ W2,
                        short* __restrict__ w1tb, short* __restrict__ w2tb)
{
    int i = blockIdx.x * 256 + threadIdx.x;
    if (i < W1T_N) {
        int k = i % FIN; int n = (i / FIN) % HH1; int e = i / (FIN * HH1);
        w1tb[i] = f2bf(W1[(size_t)e * FIN * HH1 + (size_t)k * HH1 + n]);
    } else if (i < W1T_N + W2T_N) {
        int j = i - W1T_N;
        int k = j % HH1; int n = (j / HH1) % HH2; int e = j / (HH1 * HH2);
        w2tb[j] = f2bf(W2[(size_t)e * HH1 * HH2 + (size_t)k * HH2 + n]);
    }
}

// ---- expert index + histogram ----
__global__ void k_index(const int* __restrict__ conn,
                        const int* __restrict__ elements,
                        int* __restrict__ nn,
                        int* __restrict__ counts,
                        float* __restrict__ out)
{
    __shared__ int sh[NEXP];
    int t = threadIdx.x;
    if (t < NEXP) sh[t] = 0;
    __syncthreads();
    int p = blockIdx.x * blockDim.x + t;
    int my_nn = -1;
    if (p < NP) {
        int c0 = conn[2 * p], c1 = conn[2 * p + 1];
        if (c0 != -1) {
            int b = p / Cc;
            int i0 = b * Aa + c0; if (i0 < 0) i0 += Bb * Aa;
            int i1 = b * Aa + c1; if (i1 < 0) i1 += Bb * Aa;
            my_nn = elements[i0] * NEL + elements[i1];
        }
        if (my_nn < 0 || my_nn >= NEXP) {
            out[2 * p] = 0.f; out[2 * p + 1] = 0.f;
            my_nn = -1;
        }
        nn[p] = my_nn;
        if (my_nn >= 0) atomicAdd(&sh[my_nn], 1);
    }
    __syncthreads();
    if (t < NEXP && sh[t] > 0) atomicAdd(&counts[t], sh[t]);
}

__global__ void k_scan(const int* __restrict__ counts,
                       int* __restrict__ offsets, int* __restrict__ cur,
                       int* __restrict__ tprefix)
{
    if (threadIdx.x == 0) {
        int acc = 0, tacc = 0;
        for (int e = 0; e < NEXP; ++e) {
            offsets[e] = acc; cur[e] = acc; tprefix[e] = tacc;
            acc += counts[e];
            tacc += (counts[e] + TILE_P - 1) / TILE_P;
        }
        offsets[NEXP] = acc; tprefix[NEXP] = tacc;
    }
}

__global__ void k_scatter(const int* __restrict__ nn,
                          int* __restrict__ cur, int* __restrict__ sorted)
{
    __shared__ int sh_cnt[NEXP], sh_base[NEXP];
    int t = threadIdx.x;
    if (t < NEXP) sh_cnt[t] = 0;
    __syncthreads();
    int p = blockIdx.x * blockDim.x + t;
    int e = -1, r = 0;
    if (p < NP) {
        e = nn[p];
        if (e >= 0) r = atomicAdd(&sh_cnt[e], 1);
    }
    __syncthreads();
    if (t < NEXP && sh_cnt[t] > 0) sh_base[t] = atomicAdd(&cur[t], sh_cnt[t]);
    __syncthreads();
    if (p < NP && e >= 0) sorted[sh_base[e] + r] = p;
}

// ---- MFMA MoE: one wave per 32-pair tile ----
__device__ inline const short* xptr(const short* symb, const short* pfb,
                                    int i0, int i1, int p, int kk)
{
    if (kk < FATOM)     return symb + (size_t)i0 * FATOM + kk;
    if (kk < 2 * FATOM) return symb + (size_t)i1 * FATOM + (kk - FATOM);
    return pfb + (size_t)p * FPAIR + (kk - 2 * FATOM);
}

__global__ __launch_bounds__(64) void k_moe(
    const int* __restrict__ sorted, const int* __restrict__ offsets,
    const int* __restrict__ tprefix, const int* __restrict__ conn,
    const short* __restrict__ symb, const short* __restrict__ pairfb,
    const short* __restrict__ w1tb, const short* __restrict__ w2tb,
    const float* __restrict__ b1, const float* __restrict__ b2,
    const float* __restrict__ W3, const float* __restrict__ b3,
    float* __restrict__ out)
{
    __shared__ short H1s[TILE_P * HH1];        // 8 KB, granule-XOR swizzled
    __shared__ short H2s[TILE_P * 104];        // 6.5 KB, stride 104
    __shared__ int rows_p[TILE_P], rows_i0[TILE_P], rows_i1[TILE_P];

    int tile = blockIdx.x;
    if (tile >= tprefix[NEXP]) return;
    int e = 0;
    while (tile >= tprefix[e + 1]) e++;
    int seg = offsets[e] + (tile - tprefix[e]) * TILE_P;
    int cnt = offsets[e + 1] - seg;
    if (cnt > TILE_P) cnt = TILE_P;

    int t = threadIdx.x;
    if (t < TILE_P) {
        int p = sorted[(t < cnt) ? (seg + t) : seg];   // clamp padding to row 0
        int b = p / Cc;
        rows_p[t]  = p;
        rows_i0[t] = b * Aa + conn[2 * p];
        rows_i1[t] = b * Aa + conn[2 * p + 1];
    }
    __syncthreads();

    int lr = t & 15, lg = t >> 4;

    int i0a = rows_i0[lr],      i1a = rows_i1[lr],      pa = rows_p[lr];
    int i0b = rows_i0[lr + 16], i1b = rows_i1[lr + 16], pb = rows_p[lr + 16];

    // ---------------- Layer 1: H1[32x128] = celu(X[32x384] @ W1 + b1) ----
    const short* w1t_e = w1tb + (size_t)e * HH1 * FIN;
    f32x4 acc[2][8];
#pragma unroll
    for (int nt = 0; nt < 8; ++nt) {
        float bv = b1[e * HH1 + nt * 16 + lr];
        f32x4 b4 = {bv, bv, bv, bv};
        acc[0][nt] = b4; acc[1][nt] = b4;
    }
    for (int ks = 0; ks < 12; ++ks) {
        int kk = ks * 32 + 8 * lg;
        short8 a0 = *(const short8*)xptr(symb, pairfb, i0a, i1a, pa, kk);
        short8 a1 = *(const short8*)xptr(symb, pairfb, i0b, i1b, pb, kk);
#pragma unroll
        for (int nt = 0; nt < 8; ++nt) {
            short8 bw = *(const short8*)(w1t_e + (size_t)(nt * 16 + lr) * FIN + kk);
            acc[0][nt] = __builtin_amdgcn_mfma_f32_16x16x32_bf16(a0, bw, acc[0][nt], 0, 0, 0);
            acc[1][nt] = __builtin_amdgcn_mfma_f32_16x16x32_bf16(a1, bw, acc[1][nt], 0, 0, 0);
        }
    }
    // celu + store to H1s[m][k] row-major (stride 128) with 16B-granule XOR swizzle
#pragma unroll
    for (int mt = 0; mt < 2; ++mt)
#pragma unroll
        for (int nt = 0; nt < 8; ++nt)
#pragma unroll
            for (int r2 = 0; r2 < 4; ++r2) {
                int m = mt * 16 + lg * 4 + r2;
                int n = nt * 16 + lr;
                float h = acc[mt][nt][r2];
                h = h > 0.f ? h : (__expf(h) - 1.0f);
                int ng = (n >> 3) ^ (m & 7);
                H1s[m * HH1 + ng * 8 + (n & 7)] = f2bf(h);
            }
    __syncthreads();

    // ---------------- Layer 2 (swapped): H2T[96x32] = celu(W2T @ H1T + b2)
    const short* w2t_e = w2tb + (size_t)e * HH2 * HH1;
    f32x4 acc2[6][2];
#pragma unroll
    for (int t6 = 0; t6 < 6; ++t6)
#pragma unroll
        for (int r2 = 0; r2 < 4; ++r2) {
            float bv = b2[e * HH2 + t6 * 16 + 4 * lg + r2];
            acc2[t6][0][r2] = bv; acc2[t6][1][r2] = bv;
        }
#pragma unroll
    for (int ks = 0; ks < 4; ++ks) {
        int kk = ks * 32 + 8 * lg;
        int kg = kk >> 3;
        short8 bh[2];
#pragma unroll
        for (int ntm = 0; ntm < 2; ++ntm) {
            int m = ntm * 16 + lr;
            bh[ntm] = *(const short8*)&H1s[m * HH1 + ((kg ^ (m & 7)) << 3)];
        }
#pragma unroll
        for (int t6 = 0; t6 < 6; ++t6) {
            short8 aw = *(const short8*)(w2t_e + (size_t)(t6 * 16 + lr) * HH1 + kk);
            acc2[t6][0] = __builtin_amdgcn_mfma_f32_16x16x32_bf16(aw, bh[0], acc2[t6][0], 0, 0, 0);
            acc2[t6][1] = __builtin_amdgcn_mfma_f32_16x16x32_bf16(aw, bh[1], acc2[t6][1], 0, 0, 0);
        }
    }
    // celu + store H2s[m][n2], stride 104
#pragma unroll
    for (int t6 = 0; t6 < 6; ++t6)
#pragma unroll
        for (int ntm = 0; ntm < 2; ++ntm)
#pragma unroll
            for (int r2 = 0; r2 < 4; ++r2) {
                int n2 = t6 * 16 + 4 * lg + r2;
                int m  = ntm * 16 + lr;
                float h = acc2[t6][ntm][r2];
                h = h > 0.f ? h : (__expf(h) - 1.0f);
                H2s[m * 104 + n2] = f2bf(h);
            }
    __syncthreads();

    // ---------------- Layer 3: out[32x2] = H2 @ W3 + b3 (VALU) ----------
    {
        int r = t >> 1, o = t & 1;
        if (r < cnt) {
            const float* w3e = W3 + (size_t)e * HH2 * 2;
            float s0 = b3[e * 2 + o], s1 = 0.f;
#pragma unroll
            for (int kb = 0; kb < 12; ++kb) {
                short8 h = *(const short8*)&H2s[r * 104 + kb * 8];
#pragma unroll
                for (int j = 0; j < 8; j += 2) {
                    s0 = fmaf(bf2f(h[j]),     w3e[(kb * 8 + j) * 2 + o],     s0);
                    s1 = fmaf(bf2f(h[j + 1]), w3e[(kb * 8 + j + 1) * 2 + o], s1);
                }
            }
            out[(size_t)rows_p[r] * 2 + o] = s0 + s1;
        }
    }
}

extern "C" void kernel_launch(void* const* d_in, const int* in_sizes, int n_in,
                              void* d_out, int out_size, void* d_ws, size_t ws_size,
                              hipStream_t stream)
{
    const int*   elements = (const int*)d_in[0];
    const int*   conn     = (const int*)d_in[1];
    const float* sym      = (const float*)d_in[2];
    const float* pairf    = (const float*)d_in[3];
    const float* W1       = (const float*)d_in[4];
    const float* b1       = (const float*)d_in[5];
    const float* W2       = (const float*)d_in[6];
    const float* b2       = (const float*)d_in[7];
    const float* W3       = (const float*)d_in[8];
    const float* b3       = (const float*)d_in[9];
    float* out = (float*)d_out;

    int* wsi     = (int*)d_ws;
    int* nn      = wsi + WS_NN;
    int* sorted  = wsi + WS_SORTED;
    int* counts  = wsi + WS_COUNTS;
    int* offsets = wsi + WS_OFFSETS;
    int* cur     = wsi + WS_CUR;
    int* tprefix = wsi + WS_TPREFIX;

    short* bfb    = (short*)d_ws + WS_BF_SHORT;
    short* symb   = bfb;
    short* pairfb = bfb + SYM_N;
    short* w1tb   = bfb + SYM_N + PAIR_N;
    short* w2tb   = bfb + SYM_N + PAIR_N + W1T_N;

    hipMemsetAsync((void*)counts, 0, NEXP * sizeof(int), stream);

    k_cvt_x<<<(SYM_N / 4 + PAIR_N / 4 + 255) / 256, 256, 0, stream>>>(sym, pairf, symb, pairfb);
    k_cvt_w<<<(W1T_N + W2T_N + 255) / 256, 256, 0, stream>>>(W1, W2, w1tb, w2tb);
    k_index<<<NP / 256, 256, 0, stream>>>(conn, elements, nn, counts, out);
    k_scan<<<1, 64, 0, stream>>>(counts, offsets, cur, tprefix);
    k_scatter<<<NP / 256, 256, 0, stream>>>(nn, cur, sorted);
    k_moe<<<MAX_TILES, 64, 0, stream>>>(sorted, offsets, tprefix, conn,
                                        symb, pairfb, w1tb, w2tb,
                                        b1, b2, W3, b3, out);
}